// Round 19
// baseline (209.039 us; speedup 1.0000x reference)
//
#include <hip/hip_runtime.h>
#include <math.h>

#define Nn 8192

// f32 scratch layout in d_ws (proven >= 207 KB; now using ~193 KB)
static constexpr int S1o = 256;          // 8192
static constexpr int S2o = S1o + Nn;     // 8448
static constexpr int Mo  = S2o + Nn;     // 16640: row max of Rn
static constexpr int Zo  = Mo + Nn;      // 24832: row sum of P
static constexpr int RRo = Zo + Nn;      // 33024: rowredA (mean sums) -> later rowredE
static constexpr int STo = RRo + Nn;     // 41216: mu, sig, thr(unused)
static constexpr int RBo = STo + 8;      // 41224: rowredB (var sums)
// end = 49416 floats = 193.0 KB

typedef float nfloat4 __attribute__((ext_vector_type(4)));

// ---- bit-exact f32 helpers ----
__device__ __forceinline__ float lrelu32(float z) {
    return (z >= 0.0f) ? z : __fmul_rn(0.01f, z);
}

// Branch-free f64 exp, rel err ~2^-49 (validated bit-compatible r16-r18).
__device__ __forceinline__ double exp_fast(double x) {
    x = fmin(fmax(x, -700.0), 700.0);
    const double INVLN2 = 1.44269504088896338700e+00;
    const double LN2HI  = 6.93147180369123816490e-01;
    const double LN2LO  = 1.90821492927058770002e-10;
    double nd = rint(x * INVLN2);
    double r  = fma(-nd, LN2HI, x);
    r = fma(-nd, LN2LO, r);
    double p = 1.56192069685862264622e-10;
    p = fma(p, r, 2.08767569878680989792e-09);
    p = fma(p, r, 2.50521083854417187751e-08);
    p = fma(p, r, 2.75573192239858906526e-07);
    p = fma(p, r, 2.75573192239858925110e-06);
    p = fma(p, r, 2.48015873015873015873e-05);
    p = fma(p, r, 1.98412698412698412698e-04);
    p = fma(p, r, 1.38888888888888894069e-03);
    p = fma(p, r, 8.33333333333333321769e-03);
    p = fma(p, r, 4.16666666666666643537e-02);
    p = fma(p, r, 1.66666666666666657415e-01);
    p = fma(p, r, 5.00000000000000000000e-01);
    p = fma(p, r, 1.0);
    p = fma(p, r, 1.0);
    long long n = (long long)nd;
    double sc = __longlong_as_double((n + 1023LL) << 52);
    return p * sc;
}
__device__ __forceinline__ float exp32cr(float x) {
    return (float)exp_fast((double)x);
}

__device__ float blas_dot(const float* __restrict__ a, const float* __restrict__ x, int n) {
    float lane[8];
#pragma unroll
    for (int l = 0; l < 8; ++l) lane[l] = 0.0f;
    for (int k = 0; k < n; k += 8) {
#pragma unroll
        for (int l = 0; l < 8; ++l) lane[l] = __fmaf_rn(a[k + l], x[k + l], lane[l]);
    }
    float s0 = __fadd_rn(lane[0], lane[4]);
    float s1 = __fadd_rn(lane[1], lane[5]);
    float s2 = __fadd_rn(lane[2], lane[6]);
    float s3 = __fadd_rn(lane[3], lane[7]);
    return __fadd_rn(__fadd_rn(s0, s1), __fadd_rn(s2, s3));
}

// sortable-key bijection for f32
__device__ __forceinline__ unsigned f2key(float f) {
    unsigned u = __float_as_uint(f);
    return (u & 0x80000000u) ? ~u : (u | 0x80000000u);
}
__device__ __forceinline__ float key2f(unsigned k) {
    unsigned u = (k & 0x80000000u) ? (k & 0x7FFFFFFFu) : ~k;
    return __uint_as_float(u);
}

// red[512] -> leaf-combine -> 6-level in-wave tree (bit-identical pairing).
#define ROW_REDUCE_TAIL_SHFL(RESULT_STMT)                                     \
    {                                                                         \
        __syncthreads();                                                      \
        if (t < 64) {                                                         \
            float sl = __fadd_rn(__fadd_rn(red[t * 8 + 0], red[t * 8 + 1]),   \
                                 __fadd_rn(red[t * 8 + 2], red[t * 8 + 3]));  \
            float sr = __fadd_rn(__fadd_rn(red[t * 8 + 4], red[t * 8 + 5]),   \
                                 __fadd_rn(red[t * 8 + 6], red[t * 8 + 7]));  \
            float v = __fadd_rn(sl, sr);                                      \
            _Pragma("unroll") for (int s_ = 32; s_ >= 1; s_ >>= 1) {          \
                float a_ = __shfl(v, (2 * t) & 63);                           \
                float b_ = __shfl(v, (2 * t + 1) & 63);                       \
                if (t < s_) v = __fadd_rn(a_, b_);                            \
            }                                                                 \
            if (t == 0) { float total = v; RESULT_STMT; }                     \
        }                                                                     \
        __syncthreads();                                                      \
    }

// In-place global tree over 8192 values in LDS buf A (read-regs / barrier /
// write pattern). Pairing (2i,2i+1) per level == k_tree — bit-identical.
// NT = threads participating per level loop (blockDim).
#define GLOBAL_TREE_INPLACE(Abuf, NT, TOTALVAR)                               \
    {                                                                         \
        for (int s_ = 4096; s_ >= 1; s_ >>= 1) {                              \
            float v_[16];                                                     \
            int n_ = 0;                                                       \
            for (int idx = t; idx < s_; idx += NT)                            \
                v_[n_++] = __fadd_rn(Abuf[2 * idx], Abuf[2 * idx + 1]);       \
            __syncthreads();                                                  \
            n_ = 0;                                                           \
            for (int idx = t; idx < s_; idx += NT)                            \
                Abuf[idx] = v_[n_++];                                         \
            __syncthreads();                                                  \
        }                                                                     \
        TOTALVAR = Abuf[0];                                                   \
    }

// K1: fused w + s. 32 blocks x 256.
__global__ __launch_bounds__(256) void k_s(const float* __restrict__ X,
                                           const float* __restrict__ Wr,
                                           const float* __restrict__ ar,
                                           float* __restrict__ scr) {
    __shared__ float w1[128], w2[128];
    int t = threadIdx.x;
    if (t < 128) {
        w1[t] = blas_dot(Wr + t * 64, ar, 64);
        w2[t] = blas_dot(Wr + (128 + t) * 64, ar, 64);
    }
    __syncthreads();
    int i = blockIdx.x * 256 + t;
    scr[S1o + i] = blas_dot(X + i * 128, w1, 128);
    scr[S2o + i] = blas_dot(X + i * 128, w2, 128);
}

// stats pass 0 (mean row-sums), 512 blocks x 16 rows -> rowredA (RRo).
__global__ __launch_bounds__(512) void k_stat0(const float* __restrict__ scr,
                                               float* __restrict__ rowredA) {
    __shared__ float red[512];
    int r0 = blockIdx.x * 16, t = threadIdx.x;
    int l = t >> 3, c = t & 7;
    const float* s2 = scr + S2o;
    int ebase = l * 128 + c;
    float sv[16];
#pragma unroll
    for (int k = 0; k < 16; ++k) sv[k] = s2[ebase + 8 * k];
    for (int rr = 0; rr < 16; ++rr) {
        float s1i = scr[S1o + r0 + rr];
        float r = lrelu32(__fadd_rn(s1i, sv[0]));
#pragma unroll
        for (int k = 1; k < 16; ++k)
            r = __fadd_rn(r, lrelu32(__fadd_rn(s1i, sv[k])));
        red[t] = r;
        ROW_REDUCE_TAIL_SHFL(rowredA[r0 + rr] = total)
    }
}

// stats pass 1: every block redundantly computes mu from rowredA (read-only
// here; bit-identical tree), then var row-sums -> rowredB. Block 0 also
// stores mu to scr[STo] for the downstream kernels. No races: RRo read-only,
// RBo disjoint, STo written by one block & read only by later kernels.
__global__ __launch_bounds__(512) void k_stat1(float* __restrict__ scr) {
    __shared__ float A[8192];
    __shared__ float red[512];
    int r0 = blockIdx.x * 16, t = threadIdx.x;
    const float* rowredA = scr + RRo;
    float* rowredB = scr + RBo;
    for (int idx = t; idx < 8192; idx += 512) A[idx] = rowredA[idx];
    __syncthreads();
    float total;
    GLOBAL_TREE_INPLACE(A, 512, total)
    float mu = __fdiv_rn(total, 67108864.0f);
    if (blockIdx.x == 0 && t == 0) scr[STo] = mu;

    int l = t >> 3, c = t & 7;
    const float* s2 = scr + S2o;
    int ebase = l * 128 + c;
    float sv[16];
#pragma unroll
    for (int k = 0; k < 16; ++k) sv[k] = s2[ebase + 8 * k];
    for (int rr = 0; rr < 16; ++rr) {
        float s1i = scr[S1o + r0 + rr];
        float d0 = __fsub_rn(lrelu32(__fadd_rn(s1i, sv[0])), mu);
        float r = __fmul_rn(d0, d0);
#pragma unroll
        for (int k = 1; k < 16; ++k) {
            float d = __fsub_rn(lrelu32(__fadd_rn(s1i, sv[k])), mu);
            r = __fadd_rn(r, __fmul_rn(d, d));
        }
        red[t] = r;
        ROW_REDUCE_TAIL_SHFL(rowredB[r0 + rr] = total)
    }
}

// tree over rowredB -> sig  (kept as its own tiny launch: rowredB would race
// with MZE2's rowredE writes if fused there)
__global__ __launch_bounds__(1024) void k_tree_sig(const float* __restrict__ rowredB,
                                                   float* __restrict__ scr) {
    __shared__ float A[8192];
    __shared__ float B[4096];
    int t = threadIdx.x;
    for (int idx = t; idx < 8192; idx += 1024) A[idx] = rowredB[idx];
    __syncthreads();
    float* src = A;
    float* dst = B;
    for (int s = 4096; s >= 1; s >>= 1) {
        for (int idx = t; idx < s; idx += 1024)
            dst[idx] = __fadd_rn(src[2 * idx], src[2 * idx + 1]);
        __syncthreads();
        float* tmp = src; src = dst; dst = tmp;
    }
    if (t == 0) {
        float var = __fdiv_rn(src[0], 67108864.0f);
        scr[STo + 1] = __fadd_rn(__fsqrt_rn(var), 1e-5f);
    }
}

// Fused per-row M/Z/E pass, 2 rows/block; s2 slice in registers reused.
// p[] overwrites rn[] (VGPR trim). E-sums -> RRo (rowredA dead).
__global__ __launch_bounds__(512) void k_MZE2(float* __restrict__ scr) {
    __shared__ float red[512];
    __shared__ float wmax[8];
    __shared__ float Zsh;
    float* rowredE = scr + RRo;
    int t = threadIdx.x;
    int l = t >> 3, c = t & 7;
    const float* s2 = scr + S2o;
    float mu = scr[STo], sig = scr[STo + 1];
    int ebase = l * 128 + c;
    float sv[16];
#pragma unroll
    for (int k = 0; k < 16; ++k) sv[k] = s2[ebase + 8 * k];

    for (int rr = 0; rr < 2; ++rr) {
        int i = blockIdx.x * 2 + rr;
        float s1i = scr[S1o + i];

        // phase A: Rn in registers + row max (order-free)
        float v[16];
        float mx = -3.4e38f;
#pragma unroll
        for (int k = 0; k < 16; ++k) {
            v[k] = __fdiv_rn(__fsub_rn(lrelu32(__fadd_rn(s1i, sv[k])), mu), sig);
            mx = fmaxf(mx, v[k]);
        }
#pragma unroll
        for (int o = 32; o > 0; o >>= 1) mx = fmaxf(mx, __shfl_xor(mx, o));
        if ((t & 63) == 0) wmax[t >> 6] = mx;
        __syncthreads();
        float Mi = fmaxf(fmaxf(fmaxf(wmax[0], wmax[1]), fmaxf(wmax[2], wmax[3])),
                         fmaxf(fmaxf(wmax[4], wmax[5]), fmaxf(wmax[6], wmax[7])));

        // phase B: P overwrites v, chain sum (exact NP order)
        v[0] = exp32cr(__fsub_rn(v[0], Mi));
        float r = v[0];
#pragma unroll
        for (int k = 1; k < 16; ++k) {
            v[k] = exp32cr(__fsub_rn(v[k], Mi));
            r = __fadd_rn(r, v[k]);
        }
        red[t] = r;
        ROW_REDUCE_TAIL_SHFL(Zsh = total; scr[Zo + i] = total; scr[Mo + i] = Mi)
        float Zi = Zsh;

        // phase C: E = P/Zi, same chain + leaf + tree order
        float e = __fdiv_rn(v[0], Zi);
#pragma unroll
        for (int k = 1; k < 16; ++k)
            e = __fadd_rn(e, __fdiv_rn(v[k], Zi));
        red[t] = e;
        ROW_REDUCE_TAIL_SHFL(rowredE[i] = total)
    }
}

// k_out: per-block redundant thr-tree (rowredE read-only; bit-identical
// pairing) + fused 3-way cut search + nontemporal streaming writes.
__global__ __launch_bounds__(256) void k_out(const float* __restrict__ scr,
                                             float* __restrict__ out) {
    __shared__ float A[8192];
    __shared__ unsigned kcut[8][3];
    int t = threadIdx.x;
    int r0 = blockIdx.x * 8;
    const float* rowredE = scr + RRo;
    for (int idx = t; idx < 8192; idx += 256) A[idx] = rowredE[idx];
    __syncthreads();
    float total;
    GLOBAL_TREE_INPLACE(A, 256, total)
    float mean = __fdiv_rn(total, 67108864.0f);
    float thr = __fdiv_rn(mean, 0.5f);
    float mu = scr[STo], sig = scr[STo + 1];

    if (t < 24) {
        int rr = t / 3, w = t - rr * 3;
        int i = r0 + rr;
        float s1i = scr[S1o + i];
        float Mi = scr[Mo + i], Zi = scr[Zo + i];
        double thr_d = (double)thr;
        unsigned lo = 0x00800000u;
        unsigned hi = 0xFF800000u;
        while (lo < hi) {
            unsigned mid = lo + ((hi - lo) >> 1);
            float s2v = key2f(mid);
            float Rn = __fdiv_rn(__fsub_rn(lrelu32(__fadd_rn(s1i, s2v)), mu), sig);
            float P = exp32cr(__fsub_rn(Rn, Mi));
            float E = __fdiv_rn(P, Zi);
            double m = ((double)E - thr_d) / thr_d;
            bool pred = (w == 0) ? (m >= -2.8e-8)
                      : (w == 1) ? (m > 2.8e-8)
                                 : (m >= 1.75e-7);
            if (pred) hi = mid; else lo = mid + 1;
        }
        kcut[rr][w] = lo;
    }
    __syncthreads();
    unsigned kA[8], kB[8], kC[8];
    long long rowbase[8];
#pragma unroll
    for (int rr = 0; rr < 8; ++rr) {
        kA[rr] = kcut[rr][0];
        kB[rr] = kcut[rr][1];
        kC[rr] = kcut[rr][2];
        rowbase[rr] = (long long)(r0 + rr) * Nn;
    }
    const float* s2 = scr + S2o;
    for (int ch = 0; ch < 8; ++ch) {
        int j0 = ch * 1024 + t * 4;
        nfloat4 sv = *reinterpret_cast<const nfloat4*>(s2 + j0);
        unsigned k0 = f2key(sv.x), k1 = f2key(sv.y), k2 = f2key(sv.z), k3 = f2key(sv.w);
#pragma unroll
        for (int rr = 0; rr < 8; ++rr) {
            unsigned a = kA[rr], b = kB[rr], cc = kC[rr];
            nfloat4 r;
            r.x = (k0 < a) ? 0.0f : (k0 < b) ? 1.0f : (k0 < cc) ? 0.0f : 1.0f;
            r.y = (k1 < a) ? 0.0f : (k1 < b) ? 1.0f : (k1 < cc) ? 0.0f : 1.0f;
            r.z = (k2 < a) ? 0.0f : (k2 < b) ? 1.0f : (k2 < cc) ? 0.0f : 1.0f;
            r.w = (k3 < a) ? 0.0f : (k3 < b) ? 1.0f : (k3 < cc) ? 0.0f : 1.0f;
            __builtin_nontemporal_store(r, reinterpret_cast<nfloat4*>(out + rowbase[rr] + j0));
        }
    }
}

extern "C" void kernel_launch(void* const* d_in, const int* in_sizes, int n_in,
                              void* d_out, int out_size, void* d_ws, size_t ws_size,
                              hipStream_t stream) {
    const float *X = nullptr, *Wr = nullptr, *ar = nullptr;
    for (int k = 0; k < n_in; ++k) {
        if      (in_sizes[k] == 1048576) X  = (const float*)d_in[k];
        else if (in_sizes[k] == 16384)   Wr = (const float*)d_in[k];
        else if (in_sizes[k] == 64)      ar = (const float*)d_in[k];
    }
    if (!X)  X  = (const float*)d_in[0];
    if (!Wr) Wr = (const float*)d_in[1];
    if (!ar) ar = (const float*)d_in[2];

    float* out = (float*)d_out;
    float* scr = (float*)d_ws;

    k_s        <<<32,   256, 0, stream>>>(X, Wr, ar, scr);
    k_stat0    <<<512,  512, 0, stream>>>(scr, scr + RRo);
    k_stat1    <<<512,  512, 0, stream>>>(scr);
    k_tree_sig <<<1,   1024, 0, stream>>>(scr + RBo, scr);
    k_MZE2     <<<4096, 512, 0, stream>>>(scr);
    k_out      <<<1024, 256, 0, stream>>>(scr, out);
}